// Round 9
// baseline (226.324 us; speedup 1.0000x reference)
//
#include <hip/hip_runtime.h>

typedef _Float16 h8v __attribute__((ext_vector_type(8)));
typedef float f32x4 __attribute__((ext_vector_type(4)));

#define DEVI static __device__ __forceinline__

namespace {
constexpr int B_  = 2;
constexpr int N_  = 4096;
constexpr int KS_ = 8;
constexpr int C_  = 192;
constexpr int H_  = 8;
constexpr int D_  = 24;
constexpr int NT_ = 4104;        // N_ + KS_
constexpr int NP_ = 4160;        // kv rows padded to 65*64
constexpr int DP_ = 32;          // head dim padded for K=32 MFMA
constexpr int M_  = B_ * NT_;    // 8208 total rows
constexpr int NQP_   = 4224;     // q rows padded to 33*128
constexpr int SPLIT_ = 3;        // KV-split factor
constexpr int TILES_ = NP_ / 64; // 65
constexpr int TPS_   = 22;       // ceil(65/3) tiles per split
constexpr float LOG2E_ = 1.4426950408889634f;
}

DEVI unsigned short f2h(float f) {
  union { _Float16 h; unsigned short u; } x;
  x.h = (_Float16)f;
  return x.u;
}

DEVI unsigned pkh(float lo, float hi) {
  unsigned r;
  asm("v_cvt_pkrtz_f16_f32 %0, %1, %2" : "=v"(r) : "v"(lo), "v"(hi));
  return r;
}

DEVI f32x4 mfmah(h8v a, h8v b, f32x4 c) {
  return __builtin_amdgcn_mfma_f32_16x16x32_f16(a, b, c, 0, 0, 0);
}

DEVI float exp2v(float x) {
  float r;
  asm("v_exp_f32 %0, %1" : "=v"(r) : "v"(x));
  return r;
}

DEVI float max3f(float a, float b, float c) { return fmaxf(fmaxf(a, b), c); }

DEVI void store_h4(unsigned short* dst, float4 v) {
  uint2 p;
  p.x = pkh(v.x, v.y);
  p.y = pkh(v.z, v.w);
  *reinterpret_cast<uint2*>(dst) = p;
}

// ---------------- kernel 0: prep ------------------------------------------
// Converts X||S -> Xh f16 [M_][192], [Wqkv;Wout] -> Wh f16 [768][192]
// (temp[h]*log2e folded into Wqkv's Q rows), and writes ones to Vt row d=24
// (so PV's MFMA accumulates the softmax denominator l for free).
__global__ __launch_bounds__(256) void prep_kernel(
    const float* __restrict__ X, const float* __restrict__ S,
    const float* __restrict__ Wqkv, const float* __restrict__ Wout,
    const float* __restrict__ temp,
    unsigned short* __restrict__ Xh, unsigned short* __restrict__ Wh,
    unsigned short* __restrict__ Vt)
{
  const int bx = blockIdx.x, tid = threadIdx.x;
  if (bx < 770) {                                  // Xh: 8208*192/8 = 196992 chunks
    const int c8 = bx * 256 + tid;
    if (c8 >= M_ * C_ / 8) return;
    const int e = c8 * 8, r = e / C_, c = e - (e / C_) * C_;
    const int b = r / NT_, n = r - b * NT_;
    const float* src = (n < N_) ? X + ((size_t)b * N_ + n) * C_ + c
                                : S + ((size_t)b * KS_ + (n - N_)) * C_ + c;
    const float4 v0 = *reinterpret_cast<const float4*>(src);
    const float4 v1 = *reinterpret_cast<const float4*>(src + 4);
    uint4 o;
    o.x = pkh(v0.x, v0.y); o.y = pkh(v0.z, v0.w);
    o.z = pkh(v1.x, v1.y); o.w = pkh(v1.z, v1.w);
    *reinterpret_cast<uint4*>(&Xh[e]) = o;
  } else if (bx < 842) {                           // Wh: 147456 halves, exact
    const int e = (bx - 770) * 2048 + tid * 8;
    const int row = e / C_;
    const float* src = (row < 576) ? Wqkv + e : Wout + (e - 576 * C_);
    const float sc = (row < 192) ? temp[row / 24] * LOG2E_ : 1.f;
    const float4 v0 = *reinterpret_cast<const float4*>(src);
    const float4 v1 = *reinterpret_cast<const float4*>(src + 4);
    uint4 o;
    o.x = pkh(v0.x * sc, v0.y * sc); o.y = pkh(v0.z * sc, v0.w * sc);
    o.z = pkh(v1.x * sc, v1.y * sc); o.w = pkh(v1.z * sc, v1.w * sc);
    *reinterpret_cast<uint4*>(&Wh[e]) = o;
  } else {                                         // Vt ones row d=24: 16*520 chunks
    const int c8 = (bx - 842) * 256 + tid;
    if (c8 >= 16 * (NP_ / 8)) return;
    const int bh = c8 / (NP_ / 8), nc = c8 - bh * (NP_ / 8);
    uint4 ones; ones.x = ones.y = ones.z = ones.w = 0x3C003C00u;
    *reinterpret_cast<uint4*>(&Vt[((size_t)bh * DP_ + 24) * NP_ + nc * 8]) = ones;
  }
}

// ---------------- kernel 1: QKV projection (direct-fragment GEMM) ----------
// No LDS staging, no barriers in the GEMM: A/B fragments read straight from
// global (f16, L1/L2-hot). LDS only for the epilogue repack.
__global__ __launch_bounds__(256) void qkv_kernel(
    const unsigned short* __restrict__ Xh, const unsigned short* __restrict__ Wh,
    unsigned short* __restrict__ Qb, unsigned short* __restrict__ Kb,
    unsigned short* __restrict__ Vt)
{
  __shared__ __align__(16) unsigned short Tt[64 * 72];
  const int tid = threadIdx.x, w = tid >> 6, lane = tid & 63, lr = lane & 15, lg = lane >> 4;
  const int m0 = blockIdx.x * 64;
  const int which = blockIdx.y / 3;            // 0=Q 1=K 2=V
  const int lc0 = (blockIdx.y - which * 3) * 64;
  const int o0 = blockIdx.y * 64;              // Wh row base (0..512)

  int g = m0 + w * 16 + lr; if (g > M_ - 1) g = M_ - 1;
  h8v af[6];
  #pragma unroll
  for (int kk = 0; kk < 6; ++kk)
    af[kk] = *reinterpret_cast<const h8v*>(&Xh[(size_t)g * C_ + kk * 32 + lg * 8]);

  f32x4 acc[4] = {};
  #pragma unroll
  for (int kk = 0; kk < 6; ++kk)
    #pragma unroll
    for (int f = 0; f < 4; ++f) {
      h8v bf = *reinterpret_cast<const h8v*>(&Wh[(size_t)(o0 + f * 16 + lr) * C_ + kk * 32 + lg * 8]);
      acc[f] = mfmah(af[kk], bf, acc[f]);
    }

  if (which == 2) {
    // ---- V: transpose 64x64 acc tile through LDS, coalesced stores along n
    #pragma unroll
    for (int f = 0; f < 4; ++f)
      #pragma unroll
      for (int r4 = 0; r4 < 4; ++r4)
        Tt[(f * 16 + lr) * 72 + w * 16 + lg * 4 + r4] = f2h(acc[f][r4]);
    __syncthreads();
    const int c = tid >> 2, r0 = (tid & 3) * 16;
    const int vc = lc0 + c;                         // 0..191
    const int h = (vc * 171) >> 12, d = vc - h * 24;
    const int g0 = m0 + r0;
    const bool fast = (g0 / NT_ == (g0 + 15) / NT_) && (g0 + 15 < M_);
    if (fast) {
      const int b = g0 / NT_, n0 = g0 - b * NT_;
      const size_t base = ((size_t)(b * H_ + h) * DP_ + d) * NP_ + n0;
      *reinterpret_cast<uint4*>(&Vt[base]) = *reinterpret_cast<const uint4*>(&Tt[c * 72 + r0]);
      *reinterpret_cast<uint4*>(&Vt[base + 8]) = *reinterpret_cast<const uint4*>(&Tt[c * 72 + r0 + 8]);
    } else {
      for (int j = 0; j < 16; ++j) {
        const int gg = g0 + j;
        if (gg >= M_) break;
        const int b = gg / NT_, n = gg - b * NT_;
        Vt[((size_t)(b * H_ + h) * DP_ + d) * NP_ + n] = Tt[c * 72 + r0 + j];
      }
    }
  } else {
    // ---- Q/K: repack through LDS, 2 coalesced b128 stores per thread
    #pragma unroll
    for (int f = 0; f < 4; ++f)
      #pragma unroll
      for (int r4 = 0; r4 < 4; ++r4)
        Tt[(w * 16 + lg * 4 + r4) * 72 + f * 16 + lr] = f2h(acc[f][r4]);
    __syncthreads();
    unsigned short* QK = (which == 0) ? Qb : Kb;
    #pragma unroll
    for (int i = 0; i < 2; ++i) {
      const int e = tid + 256 * i;
      const int rr = e >> 3, cc = e & 7;
      const int gg = m0 + rr;
      if (gg < M_) {
        const int b = gg / NT_, n = gg - b * NT_;
        const int oc0 = lc0 + cc * 8;               // 8|24, 8|64: never crosses a head
        const int h = (oc0 * 171) >> 12, d0 = oc0 - h * 24;
        *reinterpret_cast<uint4*>(&QK[((size_t)(b * H_ + h) * NP_ + n) * DP_ + d0]) =
            *reinterpret_cast<const uint4*>(&Tt[rr * 72 + cc * 8]);
      }
    }
  }
}

// ---------------- kernel 2: flash attention (barrier-free) -----------------
// 4 waves x 32 q-rows; KV-split over blockIdx.z. K/V fragments read DIRECTLY
// from global (L1/L2-hot, no staging, no __syncthreads). LDS holds only the
// wave-private P transpose. l accumulated via Vt's ones-column (d=24).
__global__ __launch_bounds__(256, 5) void attn_kernel(
    const unsigned short* __restrict__ Qb, const unsigned short* __restrict__ Kb,
    const unsigned short* __restrict__ Vt, float* __restrict__ Part)
{
  __shared__ __align__(16) unsigned short Pl[4][32 * 64];   // per-wave [q][kv], pswz
  const int bh = blockIdx.y, s = blockIdx.z;
  const int tid = threadIdx.x, w = tid >> 6, lane = tid & 63, lr = lane & 15, lg = lane >> 4;
  const int q0w = blockIdx.x * 128 + w * 32;
  const int t0 = s * TPS_;
  const int t1 = (t0 + TPS_ < TILES_) ? t0 + TPS_ : TILES_;
  const unsigned short* Qp = Qb + (size_t)bh * NP_ * DP_;
  const unsigned short* Kp = Kb + (size_t)bh * NP_ * DP_;
  const unsigned short* Vp = Vt + (size_t)bh * DP_ * NP_;

  h8v qf[2];
  #pragma unroll
  for (int mi = 0; mi < 2; ++mi) {
    int r = q0w + 16 * mi + lr;
    if (r > NT_ - 1) r = NT_ - 1;               // clamp (partials unread by combine)
    qf[mi] = *reinterpret_cast<const h8v*>(&Qp[(size_t)r * DP_ + lg * 8]);
  }

  // P LDS offsets (swizzle-consistent, loop-invariant)
  const int pswz = (lr & 7) ^ (((lr >> 3) & 1) << 2);
  int pw_off[2][4], pr_off[2][2];
  #pragma unroll
  for (int mi = 0; mi < 2; ++mi) {
    #pragma unroll
    for (int nf = 0; nf < 4; ++nf)
      pw_off[mi][nf] = (16 * mi + lr) * 64 + 8 * ((2 * nf + (lg >> 1)) ^ pswz) + 4 * (lg & 1);
    #pragma unroll
    for (int ks = 0; ks < 2; ++ks)
      pr_off[mi][ks] = (16 * mi + lr) * 64 + 8 * ((4 * ks + lg) ^ pswz);
  }

  unsigned short* Pw = Pl[w];
  f32x4 oacc[2][2] = {};
  float m[2] = { 0.f, 0.f };                    // m=0 start: scale-invariant

  for (int t = t0; t < t1; ++t) {
    const unsigned short* Kt = Kp + (size_t)t * 64 * DP_;
    const unsigned short* Vtt = Vp + (size_t)t * 64;

    // K fragments direct from global: rows nf*16+lr, k-slice lg*8
    h8v kf[4];
    #pragma unroll
    for (int nf = 0; nf < 4; ++nf)
      kf[nf] = *reinterpret_cast<const h8v*>(&Kt[(size_t)(nf * 16 + lr) * DP_ + lg * 8]);

    // QK^T (swapped): sa[mi][nf][r4] = S[kv = t*64+nf*16+lg*4+r4][q = q0w+16mi+lr]
    f32x4 sa[2][4];
    #pragma unroll
    for (int nf = 0; nf < 4; ++nf) {
      f32x4 z = {};
      sa[0][nf] = mfmah(kf[nf], qf[0], z);
      sa[1][nf] = mfmah(kf[nf], qf[1], z);
    }
    if (t == TILES_ - 1) {                      // only the global last tile is partial
      #pragma unroll
      for (int mi = 0; mi < 2; ++mi)
        #pragma unroll
        for (int nf = 0; nf < 4; ++nf)
          #pragma unroll
          for (int r4 = 0; r4 < 4; ++r4)
            if (t * 64 + nf * 16 + lg * 4 + r4 >= NT_) sa[mi][nf][r4] = -1e30f;
    }

    #pragma unroll
    for (int mi = 0; mi < 2; ++mi) {
      const float u0 = max3f(sa[mi][0][0], sa[mi][0][1], sa[mi][0][2]);
      const float u1 = max3f(sa[mi][0][3], sa[mi][1][0], sa[mi][1][1]);
      const float u2 = max3f(sa[mi][1][2], sa[mi][1][3], sa[mi][2][0]);
      const float u3 = max3f(sa[mi][2][1], sa[mi][2][2], sa[mi][2][3]);
      const float u4 = max3f(sa[mi][3][0], sa[mi][3][1], sa[mi][3][2]);
      float mt = max3f(max3f(u0, u1, u2), max3f(u3, u4, sa[mi][3][3]), -1e30f);
      mt = fmaxf(mt, __shfl_xor(mt, 16));
      mt = fmaxf(mt, __shfl_xor(mt, 32));

      // speculative exp with current running max (no row-sum: ones-column does l)
      #pragma unroll
      for (int nf = 0; nf < 4; ++nf)
        #pragma unroll
        for (int r4 = 0; r4 < 4; ++r4)
          sa[mi][nf][r4] = exp2v(sa[mi][nf][r4] - m[mi]);
      #pragma unroll
      for (int nf = 0; nf < 4; ++nf) {
        uint2 pu;
        pu.x = pkh(sa[mi][nf][0], sa[mi][nf][1]);
        pu.y = pkh(sa[mi][nf][2], sa[mi][nf][3]);
        *reinterpret_cast<uint2*>(&Pw[pw_off[mi][nf]]) = pu;
      }
      if (!__all(mt <= m[mi] + 8.f)) {          // rare: max grew, fix up
        const float mn = fmaxf(m[mi], mt);
        const float corr = exp2v(m[mi] - mn);
        m[mi] = mn;
        #pragma unroll
        for (int nf = 0; nf < 4; ++nf) {
          #pragma unroll
          for (int r4 = 0; r4 < 4; ++r4) sa[mi][nf][r4] *= corr;
          uint2 pu;
          pu.x = pkh(sa[mi][nf][0], sa[mi][nf][1]);
          pu.y = pkh(sa[mi][nf][2], sa[mi][nf][3]);
          *reinterpret_cast<uint2*>(&Pw[pw_off[mi][nf]]) = pu;   // rewrite (in-order DS)
        }
        #pragma unroll
        for (int r4 = 0; r4 < 4; ++r4) {
          const float ct = __shfl(corr, lg * 4 + r4);
          oacc[mi][0][r4] *= ct;                // rescales l (col 24) too
          oacc[mi][1][r4] *= ct;
        }
      }
    }

    // V fragments direct from global (includes ones-row d=24)
    h8v vbv[2][2];
    #pragma unroll
    for (int ks = 0; ks < 2; ++ks)
      #pragma unroll
      for (int df = 0; df < 2; ++df)
        vbv[ks][df] = *reinterpret_cast<const h8v*>(&Vtt[(size_t)(df * 16 + lr) * NP_ + ks * 32 + lg * 8]);

    asm volatile("s_waitcnt lgkmcnt(0)" ::: "memory");
    __builtin_amdgcn_sched_barrier(0);

    #pragma unroll
    for (int mi = 0; mi < 2; ++mi)
      #pragma unroll
      for (int ks = 0; ks < 2; ++ks) {
        h8v pa = *reinterpret_cast<const h8v*>(&Pw[pr_off[mi][ks]]);
        #pragma unroll
        for (int df = 0; df < 2; ++df)
          oacc[mi][df] = mfmah(pa, vbv[ks][df], oacc[mi][df]);
      }
  }

  // epilogue: fp32 partials (O unnormalized; m at [24], l=oacc col24 at [25])
  #pragma unroll
  for (int mi = 0; mi < 2; ++mi) {
    float mq[4];
    #pragma unroll
    for (int r4 = 0; r4 < 4; ++r4) mq[r4] = __shfl(m[mi], lg * 4 + r4);
    #pragma unroll
    for (int r4 = 0; r4 < 4; ++r4) {
      const int q = q0w + 16 * mi + lg * 4 + r4;
      float* row = Part + ((size_t)bh * NQP_ + q) * (SPLIT_ * 32) + s * 32;
      #pragma unroll
      for (int df = 0; df < 2; ++df) {
        const int d = df * 16 + lr;
        if (d < D_) row[d] = oacc[mi][df][r4];
      }
      if (lr == 8) {
        row[24] = mq[r4];
        row[25] = oacc[mi][1][r4];              // l (ones-column, col d=24)
      }
    }
  }
}

// ---------------- kernel 2b: split combine (3-way) -------------------------
__global__ __launch_bounds__(256) void combine_kernel(
    const float* __restrict__ Part, unsigned short* __restrict__ AO)
{
  const int n = blockIdx.x * 256 + threadIdx.x;
  const int bh = blockIdx.y;
  if (n >= NT_) return;
  const float* p = Part + ((size_t)bh * NQP_ + n) * (SPLIT_ * 32);
  const float m0v = p[24], m1v = p[32 + 24], m2v = p[64 + 24];
  const float l0 = p[25], l1 = p[32 + 25], l2 = p[64 + 25];
  const float mx = max3f(m0v, m1v, m2v);
  float a0 = exp2v(m0v - mx), a1 = exp2v(m1v - mx), a2 = exp2v(m2v - mx);
  const float inv = 1.f / (a0 * l0 + a1 * l1 + a2 * l2);
  a0 *= inv; a1 *= inv; a2 *= inv;
  const int b = bh >> 3, h = bh & 7;
  unsigned short* dst = AO + ((size_t)b * NT_ + n) * C_ + h * D_;
  #pragma unroll
  for (int c = 0; c < 3; ++c) {
    float4 ra, rb;
    const float* q0 = p + c * 8;
    const float* q1 = p + 32 + c * 8;
    const float* q2 = p + 64 + c * 8;
    ra.x = a0*q0[0]+a1*q1[0]+a2*q2[0];  ra.y = a0*q0[1]+a1*q1[1]+a2*q2[1];
    ra.z = a0*q0[2]+a1*q1[2]+a2*q2[2];  ra.w = a0*q0[3]+a1*q1[3]+a2*q2[3];
    rb.x = a0*q0[4]+a1*q1[4]+a2*q2[4];  rb.y = a0*q0[5]+a1*q1[5]+a2*q2[5];
    rb.z = a0*q0[6]+a1*q1[6]+a2*q2[6];  rb.w = a0*q0[7]+a1*q1[7]+a2*q2[7];
    store_h4(dst + c * 8, ra);
    store_h4(dst + c * 8 + 4, rb);
  }
}

// ---------------- kernel 3: output projection (direct-fragment) ------------
__global__ __launch_bounds__(256) void outproj_kernel(
    const unsigned short* __restrict__ AO, const unsigned short* __restrict__ Wh,
    float* __restrict__ out)
{
  const int tid = threadIdx.x, w = tid >> 6, lane = tid & 63, lr = lane & 15, lg = lane >> 4;
  const int m0 = blockIdx.x * 64, o0 = blockIdx.y * 64;

  int g = m0 + w * 16 + lr; if (g > M_ - 1) g = M_ - 1;
  h8v af[6];
  #pragma unroll
  for (int kk = 0; kk < 6; ++kk)
    af[kk] = *reinterpret_cast<const h8v*>(&AO[(size_t)g * C_ + kk * 32 + lg * 8]);

  f32x4 acc[4] = {};
  #pragma unroll
  for (int kk = 0; kk < 6; ++kk)
    #pragma unroll
    for (int f = 0; f < 4; ++f) {
      h8v bf = *reinterpret_cast<const h8v*>(&Wh[(size_t)(576 + o0 + f * 16 + lr) * C_ + kk * 32 + lg * 8]);
      acc[f] = mfmah(af[kk], bf, acc[f]);
    }

  #pragma unroll
  for (int f = 0; f < 4; ++f)
    #pragma unroll
    for (int r4 = 0; r4 < 4; ++r4) {
      const int grow = m0 + w * 16 + lg * 4 + r4;
      if (grow >= M_) continue;
      const int b = grow / NT_, n = grow % NT_;
      if (n >= N_) continue;                       // drop strategy-token rows
      out[((size_t)b * N_ + n) * C_ + o0 + f * 16 + lr] = acc[f][r4];
    }
}

// ---------------- launch ---------------------------------------------------
extern "C" void kernel_launch(void* const* d_in, const int* in_sizes, int n_in,
                              void* d_out, int out_size, void* d_ws, size_t ws_size,
                              hipStream_t stream) {
  const float* X    = (const float*)d_in[0];
  const float* S    = (const float*)d_in[1];
  const float* Wqkv = (const float*)d_in[2];
  const float* Wout = (const float*)d_in[3];
  const float* temp = (const float*)d_in[4];
  float* out = (float*)d_out;

  unsigned short* Qb = (unsigned short*)d_ws;
  const size_t qkv_elems = (size_t)B_ * H_ * NP_ * DP_;   // 2,129,920 shorts each
  unsigned short* Kb = Qb + qkv_elems;
  unsigned short* Vt = Kb + qkv_elems;
  unsigned short* AO = Vt + qkv_elems;                    // [M_][C_] f16
  unsigned short* Xh = AO + (size_t)M_ * C_;              // [M_][C_] f16
  unsigned short* Wh = Xh + (size_t)M_ * C_;              // [768][C_] f16
  float* Part = (float*)(Wh + (size_t)768 * C_);          // [bh][NQP_][SPLIT_][32] f32
  // ws total ~= 19.4 MB (f16 bufs) + 25.9 MB (Part) ~= 45.3 MB

  prep_kernel<<<875, 256, 0, stream>>>(X, S, Wqkv, Wout, temp, Xh, Wh, Vt);
  qkv_kernel<<<dim3((M_ + 63) / 64, 9), 256, 0, stream>>>(Xh, Wh, Qb, Kb, Vt);
  attn_kernel<<<dim3(NQP_ / 128, B_ * H_, SPLIT_), 256, 0, stream>>>(Qb, Kb, Vt, Part);
  combine_kernel<<<dim3((NT_ + 255) / 256, B_ * H_), 256, 0, stream>>>(Part, AO);
  outproj_kernel<<<dim3((M_ + 63) / 64, C_ / 64), 256, 0, stream>>>(AO, Wh, out);
}

// Round 10
// 175.874 us; speedup vs baseline: 1.2869x; 1.2869x over previous
//
#include <hip/hip_runtime.h>

typedef _Float16 h8v __attribute__((ext_vector_type(8)));
typedef float f32x4 __attribute__((ext_vector_type(4)));

#define DEVI static __device__ __forceinline__

namespace {
constexpr int B_  = 2;
constexpr int N_  = 4096;
constexpr int KS_ = 8;
constexpr int C_  = 192;
constexpr int H_  = 8;
constexpr int D_  = 24;
constexpr int NT_ = 4104;        // N_ + KS_
constexpr int NP_ = 4160;        // kv rows padded to 65*64
constexpr int DP_ = 32;          // head dim padded for K=32 MFMA
constexpr int M_  = B_ * NT_;    // 8208 total rows
constexpr int NQP_   = 4224;     // q rows padded to 33*128
constexpr int SPLIT_ = 3;        // KV-split factor
constexpr int TILES_ = NP_ / 64; // 65
constexpr int TPS_   = 22;       // ceil(65/3)
constexpr float LOG2E_ = 1.4426950408889634f;
}

DEVI unsigned short f2h(float f) {
  union { _Float16 h; unsigned short u; } x;
  x.h = (_Float16)f;
  return x.u;
}

DEVI unsigned pkh(float lo, float hi) {
  unsigned r;
  asm("v_cvt_pkrtz_f16_f32 %0, %1, %2" : "=v"(r) : "v"(lo), "v"(hi));
  return r;
}

DEVI f32x4 mfmah(h8v a, h8v b, f32x4 c) {
  return __builtin_amdgcn_mfma_f32_16x16x32_f16(a, b, c, 0, 0, 0);
}

DEVI float exp2v(float x) {
  float r;
  asm("v_exp_f32 %0, %1" : "=v"(r) : "v"(x));
  return r;
}

DEVI float max3f(float a, float b, float c) { return fmaxf(fmaxf(a, b), c); }

DEVI void store_h4(unsigned short* dst, float4 v) {
  uint2 p;
  p.x = pkh(v.x, v.y);
  p.y = pkh(v.z, v.w);
  *reinterpret_cast<uint2*>(dst) = p;
}

// ---------------- kernel 0: ones row for Vt (softmax-denominator column) ---
__global__ __launch_bounds__(256) void ones_kernel(unsigned short* __restrict__ Vt)
{
  const int idx = blockIdx.x * 256 + threadIdx.x;       // 16 bh x 520 chunks
  if (idx >= 16 * (NP_ / 8)) return;
  const int bh = idx / (NP_ / 8), nc = idx - bh * (NP_ / 8);
  uint4 ones; ones.x = ones.y = ones.z = ones.w = 0x3C003C00u;   // f16 1.0 x8
  *reinterpret_cast<uint4*>(&Vt[((size_t)bh * DP_ + 24) * NP_ + nc * 8]) = ones;
}

// ---------------- kernel 1: QKV projection (f16 MFMA GEMM, R6-proven) ------
__global__ __launch_bounds__(256) void qkv_kernel(
    const float* __restrict__ X, const float* __restrict__ S,
    const float* __restrict__ Wqkv, const float* __restrict__ temp,
    unsigned short* __restrict__ Qb, unsigned short* __restrict__ Kb,
    unsigned short* __restrict__ Vt)
{
  __shared__ __align__(16) unsigned short Al[64 * 200];
  __shared__ __align__(16) unsigned short Wl[64 * 200];
  const int tid = threadIdx.x;
  const int m0 = blockIdx.x * 64, o0 = blockIdx.y * 64;
  const int which = blockIdx.y / 3;            // 0=Q 1=K 2=V
  {
    const int r = tid >> 2, c0 = (tid & 3) * 48;
    const int g = m0 + r;
    if (g < M_) {
      const int b = g / NT_, n = g % NT_;
      const float* src = (n < N_) ? (X + ((size_t)b * N_ + n) * C_)
                                  : (S + ((size_t)b * KS_ + (n - N_)) * C_);
      #pragma unroll
      for (int j = 0; j < 48; j += 4)
        store_h4(&Al[r * 200 + c0 + j], *reinterpret_cast<const float4*>(src + c0 + j));
    }
    const float* wsrc = Wqkv + (size_t)(o0 + r) * C_;
    #pragma unroll
    for (int j = 0; j < 48; j += 4)
      store_h4(&Wl[r * 200 + c0 + j], *reinterpret_cast<const float4*>(wsrc + c0 + j));
  }
  __syncthreads();
  const int w = tid >> 6, lane = tid & 63, lr = lane & 15, lg = lane >> 4;
  f32x4 acc[4] = {};
  #pragma unroll
  for (int kk = 0; kk < 6; ++kk) {
    h8v af = *reinterpret_cast<const h8v*>(&Al[(w * 16 + lr) * 200 + kk * 32 + lg * 8]);
    #pragma unroll
    for (int f = 0; f < 4; ++f) {
      h8v bf = *reinterpret_cast<const h8v*>(&Wl[(f * 16 + lr) * 200 + kk * 32 + lg * 8]);
      acc[f] = mfmah(af, bf, acc[f]);
    }
  }
  const int lc0 = (blockIdx.y - which * 3) * 64;

  if (which == 2) {
    // ---- V: transpose 64x64 acc tile through LDS, coalesced stores along n
    __syncthreads();
    unsigned short* Tt = Al;                        // [c=64][r=64], stride 72
    #pragma unroll
    for (int f = 0; f < 4; ++f)
      #pragma unroll
      for (int r4 = 0; r4 < 4; ++r4)
        Tt[(f * 16 + lr) * 72 + w * 16 + lg * 4 + r4] = f2h(acc[f][r4]);
    __syncthreads();
    const int c = tid >> 2, r0 = (tid & 3) * 16;
    const int vc = lc0 + c;
    const int h = (vc * 171) >> 12, d = vc - h * 24;
    const int g0 = m0 + r0;
    const bool fast = (g0 / NT_ == (g0 + 15) / NT_) && (g0 + 15 < M_);
    if (fast) {
      const int b = g0 / NT_, n0 = g0 - b * NT_;
      const size_t base = ((size_t)(b * H_ + h) * DP_ + d) * NP_ + n0;
      *reinterpret_cast<uint4*>(&Vt[base]) = *reinterpret_cast<const uint4*>(&Tt[c * 72 + r0]);
      *reinterpret_cast<uint4*>(&Vt[base + 8]) = *reinterpret_cast<const uint4*>(&Tt[c * 72 + r0 + 8]);
    } else {
      for (int j = 0; j < 16; ++j) {
        const int gg = g0 + j;
        if (gg >= M_) break;
        const int b = gg / NT_, n = gg - b * NT_;
        Vt[((size_t)(b * H_ + h) * DP_ + d) * NP_ + n] = Tt[c * 72 + r0 + j];
      }
    }
  } else {
    // ---- Q/K: repack through LDS, 2 coalesced b128 stores per thread
    __syncthreads();
    unsigned short* Tt = Al;                        // [n-local 64][oc 64], stride 72
    #pragma unroll
    for (int f = 0; f < 4; ++f) {
      #pragma unroll
      for (int r4 = 0; r4 < 4; ++r4) {
        const int rloc = w * 16 + lg * 4 + r4;
        const int oc = lc0 + f * 16 + lr;
        float v = acc[f][r4];
        if (which == 0) v *= temp[(oc * 171) >> 12] * LOG2E_;
        Tt[rloc * 72 + f * 16 + lr] = f2h(v);
      }
    }
    __syncthreads();
    unsigned short* QK = (which == 0) ? Qb : Kb;
    #pragma unroll
    for (int i = 0; i < 2; ++i) {
      const int e = tid + 256 * i;
      const int rr = e >> 3, cc = e & 7;
      const int g = m0 + rr;
      if (g < M_) {
        const int b = g / NT_, n = g - b * NT_;
        const int oc0 = lc0 + cc * 8;               // 8|24, 8|64: never crosses a head
        const int h = (oc0 * 171) >> 12, d0 = oc0 - h * 24;
        *reinterpret_cast<uint4*>(&QK[((size_t)(b * H_ + h) * NP_ + n) * DP_ + d0]) =
            *reinterpret_cast<const uint4*>(&Tt[rr * 72 + cc * 8]);
      }
    }
  }
}

// ---------------- kernel 2: flash attention --------------------------------
// R6 skeleton (staged KV, reg-staged double buffer, 1 barrier/tile) +
// register-direct P: PV's A-operand k-axis is permuted so each lane's A-frag
// is its OWN softmax registers (zero cross-lane); V's B-frag applies the
// same k-permutation via swizzled ds_read_b64. No P LDS at all.
__global__ __launch_bounds__(256, 5) void attn_kernel(
    const unsigned short* __restrict__ Qb, const unsigned short* __restrict__ Kb,
    const unsigned short* __restrict__ Vt, float* __restrict__ Part)
{
  __shared__ __align__(16) unsigned short Kl[2][64 * 32];   // [kv][d], swz chunk^((r>>1)&3)
  __shared__ __align__(16) unsigned short Vl[2][32 * 64];   // [d][kv], swz chunk^(r&7)
  const int bh = blockIdx.y, s = blockIdx.z;
  const int tid = threadIdx.x, w = tid >> 6, lane = tid & 63, lr = lane & 15, lg = lane >> 4;
  const int q0w = blockIdx.x * 128 + w * 32;
  const int t0 = s * TPS_;
  const int t1 = (t0 + TPS_ < TILES_) ? t0 + TPS_ : TILES_;
  const unsigned short* Qp = Qb + (size_t)bh * NP_ * DP_;
  const unsigned short* Kp = Kb + (size_t)bh * NP_ * DP_;
  const unsigned short* Vp = Vt + (size_t)bh * DP_ * NP_;

  // staging: 256 threads, 1 b128 each for K (64x32) and V (32x64)
  const int kR = tid >> 2, kC = tid & 3;
  const int vR = tid >> 3, vC = tid & 7;
  const int kw_off = kR * 32 + 8 * (kC ^ ((kR >> 1) & 3));
  const int vw_off = vR * 64 + 8 * (vC ^ (vR & 7));
  const unsigned short* Kg = Kp + (size_t)kR * DP_ + kC * 8;
  const unsigned short* Vg = Vp + (size_t)vR * NP_ + vC * 8;

  h8v qf[2];
  #pragma unroll
  for (int mi = 0; mi < 2; ++mi) {
    int r = q0w + 16 * mi + lr;
    if (r > NT_ - 1) r = NT_ - 1;               // clamp (partials unread by combine)
    qf[mi] = *reinterpret_cast<const h8v*>(&Qp[(size_t)r * DP_ + lg * 8]);
  }

  // fragment read offsets (swizzle-consistent, loop-invariant)
  int kr_off[4];
  #pragma unroll
  for (int nf = 0; nf < 4; ++nf)
    kr_off[nf] = (nf * 16 + lr) * 32 + 8 * (lg ^ ((lr >> 1) & 3));
  // V b64 reads: [ks][jh][df]; kv group (2ks+jh)*16 + lg*4 -> chunk/half swizzled by row
  int vr_off[2][2][2];
  #pragma unroll
  for (int ks = 0; ks < 2; ++ks)
    #pragma unroll
    for (int jh = 0; jh < 2; ++jh)
      #pragma unroll
      for (int df = 0; df < 2; ++df)
        vr_off[ks][jh][df] = (df * 16 + lr) * 64 +
                             8 * (((2 * ks + jh) * 2 + (lg >> 1)) ^ (lr & 7)) +
                             4 * (lg & 1);

  f32x4 oacc[2][2] = {};
  float m[2] = { 0.f, 0.f };                    // m=0 start: scale-invariant

  // prologue: stage first tile into buffer 0
  *reinterpret_cast<h8v*>(&Kl[0][kw_off]) = *reinterpret_cast<const h8v*>(Kg + (size_t)t0 * 64 * DP_);
  *reinterpret_cast<h8v*>(&Vl[0][vw_off]) = *reinterpret_cast<const h8v*>(Vg + t0 * 64);
  __syncthreads();

  int cur = 0;
  for (int t = t0; t < t1; ++t) {
    h8v kreg, vreg;
    const bool more = (t + 1 < t1);
    if (more) {
      kreg = *reinterpret_cast<const h8v*>(Kg + (size_t)(t + 1) * 64 * DP_);
      vreg = *reinterpret_cast<const h8v*>(Vg + (t + 1) * 64);
    }
    const unsigned short* Kc = Kl[cur];
    const unsigned short* Vc = Vl[cur];

    // QK^T (swapped): sa[mi][nf][r4] = S[kv = t*64+nf*16+lg*4+r4][q = q0w+16mi+lr]
    h8v kf[4];
    #pragma unroll
    for (int nf = 0; nf < 4; ++nf)
      kf[nf] = *reinterpret_cast<const h8v*>(&Kc[kr_off[nf]]);
    f32x4 sa[2][4];
    #pragma unroll
    for (int nf = 0; nf < 4; ++nf) {
      f32x4 z = {};
      sa[0][nf] = mfmah(kf[nf], qf[0], z);
      sa[1][nf] = mfmah(kf[nf], qf[1], z);
    }
    if (t == TILES_ - 1) {
      #pragma unroll
      for (int mi = 0; mi < 2; ++mi)
        #pragma unroll
        for (int nf = 0; nf < 4; ++nf)
          #pragma unroll
          for (int r4 = 0; r4 < 4; ++r4)
            if (t * 64 + nf * 16 + lg * 4 + r4 >= NT_) sa[mi][nf][r4] = -1e30f;
    }

    // V B-frags (tile-shared, k-permuted layout; includes ones-row d=24)
    h8v vb[2][2];
    #pragma unroll
    for (int ks = 0; ks < 2; ++ks)
      #pragma unroll
      for (int df = 0; df < 2; ++df) {
        const uint2 lo = *reinterpret_cast<const uint2*>(&Vc[vr_off[ks][0][df]]);
        const uint2 hi = *reinterpret_cast<const uint2*>(&Vc[vr_off[ks][1][df]]);
        union { uint4 u; h8v h; } bu;
        bu.u = make_uint4(lo.x, lo.y, hi.x, hi.y);
        vb[ks][df] = bu.h;
      }

    #pragma unroll
    for (int mi = 0; mi < 2; ++mi) {
      // tile max (f32 tree) + cross-group reduce
      const float u0 = max3f(sa[mi][0][0], sa[mi][0][1], sa[mi][0][2]);
      const float u1 = max3f(sa[mi][0][3], sa[mi][1][0], sa[mi][1][1]);
      const float u2 = max3f(sa[mi][1][2], sa[mi][1][3], sa[mi][2][0]);
      const float u3 = max3f(sa[mi][2][1], sa[mi][2][2], sa[mi][2][3]);
      const float u4 = max3f(sa[mi][3][0], sa[mi][3][1], sa[mi][3][2]);
      float mt = max3f(max3f(u0, u1, u2), max3f(u3, u4, sa[mi][3][3]), -1e30f);
      mt = fmaxf(mt, __shfl_xor(mt, 16));
      mt = fmaxf(mt, __shfl_xor(mt, 32));

      // speculative exp with current running max (ones-column accumulates l)
      #pragma unroll
      for (int nf = 0; nf < 4; ++nf)
        #pragma unroll
        for (int r4 = 0; r4 < 4; ++r4)
          sa[mi][nf][r4] = exp2v(sa[mi][nf][r4] - m[mi]);

      if (!__all(mt <= m[mi] + 8.f)) {          // rare: max grew, rescale
        const float mn = fmaxf(m[mi], mt);
        const float corr = exp2v(m[mi] - mn);
        m[mi] = mn;
        #pragma unroll
        for (int nf = 0; nf < 4; ++nf)
          #pragma unroll
          for (int r4 = 0; r4 < 4; ++r4) sa[mi][nf][r4] *= corr;
        #pragma unroll
        for (int r4 = 0; r4 < 4; ++r4) {
          const float ct = __shfl(corr, lg * 4 + r4);
          oacc[mi][0][r4] *= ct;                // rescales l (col 24) too
          oacc[mi][1][r4] *= ct;
        }
      }

      // A-frags = own registers packed to f16 (k-permuted layout, no LDS)
      union { uint4 u; h8v h; } a0u, a1u;
      a0u.u.x = pkh(sa[mi][0][0], sa[mi][0][1]);
      a0u.u.y = pkh(sa[mi][0][2], sa[mi][0][3]);
      a0u.u.z = pkh(sa[mi][1][0], sa[mi][1][1]);
      a0u.u.w = pkh(sa[mi][1][2], sa[mi][1][3]);
      a1u.u.x = pkh(sa[mi][2][0], sa[mi][2][1]);
      a1u.u.y = pkh(sa[mi][2][2], sa[mi][2][3]);
      a1u.u.z = pkh(sa[mi][3][0], sa[mi][3][1]);
      a1u.u.w = pkh(sa[mi][3][2], sa[mi][3][3]);

      #pragma unroll
      for (int df = 0; df < 2; ++df) {
        oacc[mi][df] = mfmah(a0u.h, vb[0][df], oacc[mi][df]);
        oacc[mi][df] = mfmah(a1u.h, vb[1][df], oacc[mi][df]);
      }
    }

    if (more) {
      *reinterpret_cast<h8v*>(&Kl[cur ^ 1][kw_off]) = kreg;
      *reinterpret_cast<h8v*>(&Vl[cur ^ 1][vw_off]) = vreg;
    }
    __syncthreads();
    cur ^= 1;
  }

  // epilogue: fp32 partials (O unnormalized; m at [24], l=oacc col24 at [25])
  #pragma unroll
  for (int mi = 0; mi < 2; ++mi) {
    float mq[4];
    #pragma unroll
    for (int r4 = 0; r4 < 4; ++r4) mq[r4] = __shfl(m[mi], lg * 4 + r4);
    #pragma unroll
    for (int r4 = 0; r4 < 4; ++r4) {
      const int q = q0w + 16 * mi + lg * 4 + r4;
      float* row = Part + ((size_t)bh * NQP_ + q) * (SPLIT_ * 32) + s * 32;
      #pragma unroll
      for (int df = 0; df < 2; ++df) {
        const int d = df * 16 + lr;
        if (d < D_) row[d] = oacc[mi][df][r4];
      }
      if (lr == 8) {
        row[24] = mq[r4];
        row[25] = oacc[mi][1][r4];              // l (ones-column, col d=24)
      }
    }
  }
}

// ---------------- kernel 2b: split combine (3-way) -------------------------
__global__ __launch_bounds__(256) void combine_kernel(
    const float* __restrict__ Part, unsigned short* __restrict__ AO)
{
  const int n = blockIdx.x * 256 + threadIdx.x;
  const int bh = blockIdx.y;
  if (n >= NT_) return;
  const float* p = Part + ((size_t)bh * NQP_ + n) * (SPLIT_ * 32);
  const float m0v = p[24], m1v = p[32 + 24], m2v = p[64 + 24];
  const float l0 = p[25], l1 = p[32 + 25], l2 = p[64 + 25];
  const float mx = max3f(m0v, m1v, m2v);
  float a0 = exp2v(m0v - mx), a1 = exp2v(m1v - mx), a2 = exp2v(m2v - mx);
  const float inv = 1.f / (a0 * l0 + a1 * l1 + a2 * l2);
  a0 *= inv; a1 *= inv; a2 *= inv;
  const int b = bh >> 3, h = bh & 7;
  unsigned short* dst = AO + ((size_t)b * NT_ + n) * C_ + h * D_;
  #pragma unroll
  for (int c = 0; c < 3; ++c) {
    float4 ra, rb;
    const float* q0 = p + c * 8;
    const float* q1 = p + 32 + c * 8;
    const float* q2 = p + 64 + c * 8;
    ra.x = a0*q0[0]+a1*q1[0]+a2*q2[0];  ra.y = a0*q0[1]+a1*q1[1]+a2*q2[1];
    ra.z = a0*q0[2]+a1*q1[2]+a2*q2[2];  ra.w = a0*q0[3]+a1*q1[3]+a2*q2[3];
    rb.x = a0*q0[4]+a1*q1[4]+a2*q2[4];  rb.y = a0*q0[5]+a1*q1[5]+a2*q2[5];
    rb.z = a0*q0[6]+a1*q1[6]+a2*q2[6];  rb.w = a0*q0[7]+a1*q1[7]+a2*q2[7];
    store_h4(dst + c * 8, ra);
    store_h4(dst + c * 8 + 4, rb);
  }
}

// ---------------- kernel 3: output projection (R6-proven) ------------------
__global__ __launch_bounds__(256) void outproj_kernel(
    const unsigned short* __restrict__ AO, const float* __restrict__ Wout,
    float* __restrict__ out)
{
  __shared__ __align__(16) unsigned short Al[64 * 200];
  __shared__ __align__(16) unsigned short Wl[64 * 200];
  const int tid = threadIdx.x;
  const int m0 = blockIdx.x * 64, o0 = blockIdx.y * 64;
  {
    const int r = tid >> 2, c0 = (tid & 3) * 48;
    int g = m0 + r; if (g > M_ - 1) g = M_ - 1;
    #pragma unroll
    for (int j = 0; j < 48; j += 8)
      *reinterpret_cast<uint4*>(&Al[r * 200 + c0 + j]) =
          *reinterpret_cast<const uint4*>(&AO[(size_t)g * C_ + c0 + j]);
    const float* wsrc = Wout + (size_t)(o0 + r) * C_;
    #pragma unroll
    for (int j = 0; j < 48; j += 4)
      store_h4(&Wl[r * 200 + c0 + j], *reinterpret_cast<const float4*>(wsrc + c0 + j));
  }
  __syncthreads();
  const int w = tid >> 6, lane = tid & 63, lr = lane & 15, lg = lane >> 4;
  f32x4 acc[4] = {};
  #pragma unroll
  for (int kk = 0; kk < 6; ++kk) {
    h8v af = *reinterpret_cast<const h8v*>(&Al[(w * 16 + lr) * 200 + kk * 32 + lg * 8]);
    #pragma unroll
    for (int f = 0; f < 4; ++f) {
      h8v bf = *reinterpret_cast<const h8v*>(&Wl[(f * 16 + lr) * 200 + kk * 32 + lg * 8]);
      acc[f] = mfmah(af, bf, acc[f]);
    }
  }
  #pragma unroll
  for (int f = 0; f < 4; ++f)
    #pragma unroll
    for (int r4 = 0; r4 < 4; ++r4) {
      const int grow = m0 + w * 16 + lg * 4 + r4;
      if (grow >= M_) continue;
      const int b = grow / NT_, n = grow % NT_;
      if (n >= N_) continue;                       // drop strategy-token rows
      out[((size_t)b * N_ + n) * C_ + o0 + f * 16 + lr] = acc[f][r4];
    }
}

// ---------------- launch ---------------------------------------------------
extern "C" void kernel_launch(void* const* d_in, const int* in_sizes, int n_in,
                              void* d_out, int out_size, void* d_ws, size_t ws_size,
                              hipStream_t stream) {
  const float* X    = (const float*)d_in[0];
  const float* S    = (const float*)d_in[1];
  const float* Wqkv = (const float*)d_in[2];
  const float* Wout = (const float*)d_in[3];
  const float* temp = (const float*)d_in[4];
  float* out = (float*)d_out;

  unsigned short* Qb = (unsigned short*)d_ws;
  const size_t qkv_elems = (size_t)B_ * H_ * NP_ * DP_;   // 2,129,920 shorts each
  unsigned short* Kb = Qb + qkv_elems;
  unsigned short* Vt = Kb + qkv_elems;
  unsigned short* AO = Vt + qkv_elems;                    // [M_][C_] f16
  float* Part = (float*)(AO + (size_t)M_ * C_);           // [bh][NQP_][SPLIT_][32] f32
  // ws: 16.0 MB (f16 bufs) + 25.9 MB (Part) ~= 42 MB

  ones_kernel<<<33, 256, 0, stream>>>(Vt);
  qkv_kernel<<<dim3((M_ + 63) / 64, 9), 256, 0, stream>>>(X, S, Wqkv, temp, Qb, Kb, Vt);
  attn_kernel<<<dim3(NQP_ / 128, B_ * H_, SPLIT_), 256, 0, stream>>>(Qb, Kb, Vt, Part);
  combine_kernel<<<dim3((NT_ + 255) / 256, B_ * H_), 256, 0, stream>>>(Part, AO);
  outproj_kernel<<<dim3((M_ + 63) / 64, C_ / 64), 256, 0, stream>>>(AO, Wout, out);
}